// Round 2
// baseline (228.777 us; speedup 1.0000x reference)
//
#include <hip/hip_runtime.h>

// FM forward, MI355X.
// inputs: cat[B,26] i32, num[B,13] f32, Wc[26,100000,16] f32, bc[26,100000] f32,
//         Wn[13,16] f32, bn[13] f32, b0[1] f32  ->  out[B,1] f32
constexpr int B     = 16384;
constexpr int F_CAT = 26;
constexpr int CARD  = 100000;
constexpr int F_NUM = 13;
constexpr int D     = 16;

// 4 lanes per batch row; lane sub owns dims [4*sub, 4*sub+4).
// Every term (0.5*(||s||^2 - sum||v||^2), 1st-order biases) is additive
// across lanes, so a 2-step shfl_xor reduce finishes the row.
__global__ __launch_bounds__(256) void fm_fwd(
    const int*   __restrict__ cat,   // [B, F_CAT]
    const float* __restrict__ num,   // [B, F_NUM]
    const float* __restrict__ Wc,    // [F_CAT, CARD, D]
    const float* __restrict__ bc,    // [F_CAT, CARD]
    const float* __restrict__ Wn,    // [F_NUM, D]
    const float* __restrict__ bn,    // [F_NUM]
    const float* __restrict__ b0,    // [1]
    float*       __restrict__ out)   // [B]
{
    const int tid = blockIdx.x * blockDim.x + threadIdx.x;
    const int row = tid >> 2;
    const int sub = tid & 3;
    if (row >= B) return;

    // 26 indices for this row, vectorized: 6x int4 + 1x int2.
    // (Redundant across the row's 4 lanes; L1 broadcasts.)
    int idx[F_CAT];
    {
        const int* cp = cat + row * F_CAT;
#pragma unroll
        for (int q = 0; q < 6; ++q) {
            const int4 v = *reinterpret_cast<const int4*>(cp + q * 4);
            idx[q * 4 + 0] = v.x; idx[q * 4 + 1] = v.y;
            idx[q * 4 + 2] = v.z; idx[q * 4 + 3] = v.w;
        }
        const int2 t = *reinterpret_cast<const int2*>(cp + 24);
        idx[24] = t.x; idx[25] = t.y;
    }

    // 1st-order bc gathers first (6-7 per lane), so they are in flight
    // alongside the Wc gathers below before anything waits.
    float acc = 0.f;
#pragma unroll
    for (int f = sub; f < F_CAT; f += 4) {
        acc += bc[(size_t)f * CARD + (size_t)idx[f]];
    }

    float4 s = make_float4(0.f, 0.f, 0.f, 0.f);
    float ssq = 0.f;   // partial sum of ||v_i||^2 over this lane's dims

    // 26 independent float4 gathers — fully unrolled, all in flight.
    // Row base is 64B-aligned; 4 lanes cover one contiguous 64B row.
#pragma unroll
    for (int f = 0; f < F_CAT; ++f) {
        const float4 v = *reinterpret_cast<const float4*>(
            Wc + ((size_t)f * CARD + (size_t)idx[f]) * D + sub * 4);
        s.x += v.x; s.y += v.y; s.z += v.z; s.w += v.w;
        ssq += v.x * v.x + v.y * v.y + v.z * v.z + v.w * v.w;
    }

    // Numerical part: Vn_i = x_i * Wn[i]; tiny dense tables, L1/L2-resident.
#pragma unroll
    for (int i = 0; i < F_NUM; ++i) {
        const float x = num[row * F_NUM + i];
        const float4 w = *reinterpret_cast<const float4*>(Wn + i * D + sub * 4);
        s.x += x * w.x; s.y += x * w.y; s.z += x * w.z; s.w += x * w.w;
        ssq += x * x * (w.x * w.x + w.y * w.y + w.z * w.z + w.w * w.w);
    }
#pragma unroll
    for (int i = sub; i < F_NUM; i += 4) {
        acc += num[row * F_NUM + i] * bn[i];
    }

    // Per-lane partial; additive across the 4 lanes of this row.
    float part = 0.5f * (s.x * s.x + s.y * s.y + s.z * s.z + s.w * s.w - ssq) + acc;
    part += __shfl_xor(part, 1);
    part += __shfl_xor(part, 2);

    if (sub == 0) out[row] = part + b0[0];
}

extern "C" void kernel_launch(void* const* d_in, const int* in_sizes, int n_in,
                              void* d_out, int out_size, void* d_ws, size_t ws_size,
                              hipStream_t stream) {
    const int*   cat = (const int*)  d_in[0];
    const float* num = (const float*)d_in[1];
    const float* Wc  = (const float*)d_in[2];
    const float* bc  = (const float*)d_in[3];
    const float* Wn  = (const float*)d_in[4];
    const float* bn  = (const float*)d_in[5];
    const float* b0  = (const float*)d_in[6];
    float*       out = (float*)d_out;

    const int threads = B * 4;          // 4 lanes per row
    const int block   = 256;
    const int grid    = (threads + block - 1) / block;  // 256 blocks
    fm_fwd<<<grid, block, 0, stream>>>(cat, num, Wc, bc, Wn, bn, b0, out);
}

// Round 6
// 227.046 us; speedup vs baseline: 1.0076x; 1.0076x over previous
//
#include <hip/hip_runtime.h>

// FM forward, MI355X — gather-latency-bound; maximize waves in flight.
// inputs: cat[B,26] i32, num[B,13] f32, Wc[26,100000,16] f32, bc[26,100000] f32,
//         Wn[13,16] f32, bn[13] f32, b0[1] f32  ->  out[B,1] f32
constexpr int B     = 16384;
constexpr int F_CAT = 26;
constexpr int CARD  = 100000;
constexpr int F_NUM = 13;
constexpr int D     = 16;

// 32 lanes per row: lane = half*16 + d. half in {0,1} owns features
// [half*13, half*13+13); d owns dim d. A Wc load instruction's 16
// consecutive lanes cover one contiguous 64B row segment -> one L2
// request per feature gather, and 512K threads -> 2048 blocks ->
// 32 waves/CU (full occupancy) for latency hiding.
//
// interaction = 0.5*(sum_d s_d^2 - SSQ). Per-lane s is a half-sum over
// this half's features; combine halves with shfl_xor(s,16) before
// squaring; each dim then appears twice -> weight s_full^2 by 0.25.
__global__ __launch_bounds__(256) void fm_fwd(
    const int*   __restrict__ cat,   // [B, F_CAT]
    const float* __restrict__ num,   // [B, F_NUM]
    const float* __restrict__ Wc,    // [F_CAT, CARD, D]
    const float* __restrict__ bc,    // [F_CAT, CARD]
    const float* __restrict__ Wn,    // [F_NUM, D]
    const float* __restrict__ bn,    // [F_NUM]
    const float* __restrict__ b0,    // [1]
    float*       __restrict__ out)   // [B]
{
    const int tid  = blockIdx.x * blockDim.x + threadIdx.x;
    const int row  = tid >> 5;
    const int l32  = tid & 31;
    const int half = l32 >> 4;
    const int d    = l32 & 15;

    const int fbase = half * 13;
    const int* rowc = cat + row * F_CAT + fbase;

    // 13 indices for this lane's feature half (scalar loads: 104B row
    // stride means no guaranteed 16B alignment; addresses are uniform
    // across the 16-lane group -> L1 broadcast, cheap).
    int idx[13];
#pragma unroll
    for (int i = 0; i < 13; ++i) idx[i] = rowc[i];

    // 1st-order bias gather issued first: lane d<13 handles feature
    // fbase+d, so it rides the queue with the Wc gathers below.
    float acc = 0.f;
    if (d < 13) acc = bc[(size_t)(fbase + d) * CARD + (size_t)idx[d]];

    // 13 independent 4B gathers, all in flight before any use
    float v[13];
#pragma unroll
    for (int i = 0; i < 13; ++i) {
        v[i] = Wc[((size_t)(fbase + i) * CARD + (size_t)idx[i]) * D + d];
    }

    float s = 0.f, ssq = 0.f;
#pragma unroll
    for (int i = 0; i < 13; ++i) { s += v[i]; ssq += v[i] * v[i]; }

    // numerical features: half 0 folds them into s/ssq; half 1 takes
    // the numerical 1st-order bias (load balance; tables L1-hot)
    if (half == 0) {
        const float* nr = num + row * F_NUM;
#pragma unroll
        for (int i = 0; i < F_NUM; ++i) {
            const float x  = nr[i];
            const float vx = x * Wn[i * D + d];
            s += vx; ssq += vx * vx;
        }
    } else if (d < 13) {
        acc += num[row * F_NUM + d] * bn[d];
    }

    // combine the two feature-halves of s_d, then reduce everything
    const float s_full = s + __shfl_xor(s, 16);
    float t = 0.25f * s_full * s_full - 0.5f * ssq + acc;
    t += __shfl_xor(t, 1);
    t += __shfl_xor(t, 2);
    t += __shfl_xor(t, 4);
    t += __shfl_xor(t, 8);
    t += __shfl_xor(t, 16);

    if (l32 == 0) out[row] = t + b0[0];
}

extern "C" void kernel_launch(void* const* d_in, const int* in_sizes, int n_in,
                              void* d_out, int out_size, void* d_ws, size_t ws_size,
                              hipStream_t stream) {
    const int*   cat = (const int*)  d_in[0];
    const float* num = (const float*)d_in[1];
    const float* Wc  = (const float*)d_in[2];
    const float* bc  = (const float*)d_in[3];
    const float* Wn  = (const float*)d_in[4];
    const float* bn  = (const float*)d_in[5];
    const float* b0  = (const float*)d_in[6];
    float*       out = (float*)d_out;

    const int threads = B * 32;          // 32 lanes per row
    const int block   = 256;
    const int grid    = threads / block; // 2048 blocks -> 8/CU, 32 waves/CU
    fm_fwd<<<grid, block, 0, stream>>>(cat, num, Wc, bc, Wn, bn, b0, out);
}